// Round 10
// baseline (661.153 us; speedup 1.0000x reference)
//
#include <hip/hip_runtime.h>
#include <hip/hip_bf16.h>

typedef unsigned short u16;
typedef unsigned int   u32;
typedef unsigned long long u64;
typedef __attribute__((ext_vector_type(8))) short bf16x8;
typedef __attribute__((ext_vector_type(2))) float f32x2;
typedef __attribute__((ext_vector_type(4))) float f32x4;
typedef __attribute__((ext_vector_type(16))) float f32x16;

#define MFMA16(a,b,c) __builtin_amdgcn_mfma_f32_16x16x32_bf16(a,b,c,0,0,0)
#define MFMA32(a,b,c) __builtin_amdgcn_mfma_f32_32x32x16_bf16(a,b,c,0,0,0)

// ---- problem dims ----
#define NV_   321
#define B_    16
#define L_    512
#define D_    128
#define P_    64
#define E_    8
#define H_    512
#define NRW   5136        // B*NV
#define NTOK  328704      // NRW*P
#define DP_   8192        // D*P
#define NBUCK 329728      // NTOK + 8*128 padding

static __device__ __forceinline__ u16 f2bf(float f){
  __hip_bfloat16 h = __float2bfloat16(f);
  return *reinterpret_cast<u16*>(&h);
}

// packed sigma-form tanh-GELU on 2 lanes: x*sigma(1.5958x(1+0.044715x^2))
static __device__ __forceinline__ f32x2 gelu2(f32x2 x){
  f32x2 x2 = x*x;
  f32x2 p  = x2 * (-0.1029433f) + (-2.3022083f);   // v_pk_fma
  f32x2 a  = x*p;
  f32x2 en;
  en.x = exp2f(a.x); en.y = exp2f(a.y);
  f32x2 den = en + 1.0f;
  f32x2 r;
  r.x = __builtin_amdgcn_rcpf(den.x);
  r.y = __builtin_amdgcn_rcpf(den.y);
  return x*r;
}

static __device__ __forceinline__ u32 bfadd2(u32 a, u32 b){
  float lo = __uint_as_float(a<<16)           + __uint_as_float(b<<16);
  float hi = __uint_as_float(a&0xffff0000u)   + __uint_as_float(b&0xffff0000u);
  return (u32)f2bf(lo) | ((u32)f2bf(hi)<<16);
}

// ============ workspace layout (bytes) — end ~193 MB (budget 256 MiB) ============
static constexpr size_t alup(size_t x){ return (x + 255) & ~(size_t)255; }
static constexpr size_t OFF_MEAN = 0;
static constexpr size_t OFF_RSTD = OFF_MEAN + alup((size_t)NRW*4);
static constexpr size_t OFF_STD  = OFF_RSTD + alup((size_t)NRW*4);
static constexpr size_t OFF_XT   = OFF_STD  + alup((size_t)NRW*4);
static constexpr size_t OFF_PE   = OFF_XT   + alup((size_t)NRW*L_*4);
static constexpr size_t OFF_W1T  = OFF_PE   + alup((size_t)P_*D_*4);
static constexpr size_t OFF_W2T  = OFF_W1T  + alup((size_t)E_*H_*D_*2);
static constexpr size_t OFF_WHT  = OFF_W2T  + alup((size_t)E_*D_*H_*2);
static constexpr size_t OFF_T    = OFF_WHT  + alup((size_t)96*DP_*2);      // tokens bf16; later ALIASED as dec8
static constexpr size_t OFF_TOPI = OFF_T    + alup((size_t)NTOK*D_*2);
static constexpr size_t OFF_GATE = OFF_TOPI + alup((size_t)NTOK*4);
static constexpr size_t OFF_CNTR = OFF_GATE + alup((size_t)NTOK*8);
static constexpr size_t OFF_BTOK = OFF_CNTR + alup((size_t)1024);
static constexpr size_t OFF_BGT  = OFF_BTOK + alup((size_t)2*NBUCK*4);
static constexpr size_t OFF_OUT  = OFF_BGT  + alup((size_t)2*NBUCK*4);     // combined token outputs bf16 [token][d]
static constexpr size_t OFF_MEAND= OFF_OUT  + alup((size_t)NTOK*D_*2);
static constexpr size_t OFF_RSTDD= OFF_MEAND+ alup((size_t)NRW*8);
static constexpr size_t OFF_WVG  = OFF_RSTDD+ alup((size_t)NRW*8);
static constexpr size_t OFF_PEG  = OFF_WVG  + alup((size_t)16*8*8);
static constexpr size_t OFF_PG   = OFF_PEG  + alup((size_t)P_*E_*8);
static constexpr size_t OFF_PI   = OFF_PG   + alup((size_t)NRW*12*4);

// ci ints at OFF_CNTR+128: [16..23]=cur1 [24..31]=cur2
// [32..40]=start1 [41..49]=start2 [50..58]=bstart1 [59..67]=bstart2

// ============ kernels ============

__global__ void k_xt(const float* __restrict__ x, float* __restrict__ xT){
  __shared__ float tile[32][33];
  int b = blockIdx.z;
  int v0 = blockIdx.x*32, l0 = blockIdx.y*32;
  int tx = threadIdx.x, ty = threadIdx.y;
  for(int i=ty;i<32;i+=8){
    int l = l0+i, v = v0+tx;
    tile[i][tx] = (v<NV_) ? x[((size_t)b*L_ + l)*NV_ + v] : 0.f;
  }
  __syncthreads();
  for(int i=ty;i<32;i+=8){
    int v = v0+i, l = l0+tx;
    if(v<NV_) xT[((size_t)(b*NV_+v))*L_ + l] = tile[tx][i];
  }
}

__global__ void k_stats(const float* __restrict__ xT, float* meanp, float* rstdp, float* stdp,
                        double* meand, double* rstdd){
  __shared__ double s1[256], s2[256];
  int r = blockIdx.x, t = threadIdx.x;
  double a = (double)xT[(size_t)r*L_ + t], b = (double)xT[(size_t)r*L_ + 256 + t];
  s1[t]=a+b; s2[t]=a*a+b*b;
  __syncthreads();
  for(int o=128;o>0;o>>=1){ if(t<o){ s1[t]+=s1[t+o]; s2[t]+=s2[t+o]; } __syncthreads(); }
  if(t==0){
    double m = s1[0]*(1.0/512.0);
    double var = s2[0]*(1.0/512.0) - m*m;
    double sd = sqrt(var + 1e-5);
    meanp[r]=(float)m; stdp[r]=(float)sd; rstdp[r]=(float)(1.0/sd);
    meand[r]=m; rstdd[r]=1.0/sd;
  }
}

// PE (float32 np semantics) + Wvg=W_val@W_g, peg=pe@W_g in fp64, one block
__global__ void k_prep(const float* __restrict__ Wval, const float* __restrict__ Wg,
                       float* __restrict__ pef, double* __restrict__ Wvg,
                       double* __restrict__ peg){
  int t = threadIdx.x;
  for(int i=t;i<8192;i+=256){
    int p = i>>7, d = i&127, k = d>>1;
    double div = exp(-(double)(2*k) * (9.210340371976184 /128.0)); // ln(10000)/128
    double ang = (double)p * div;
    double v = (d&1) ? cos(ang) : sin(ang);
    pef[i] = (float)v;
  }
  __syncthreads();
  if(t<128){
    int j = t>>3, e = t&7;
    double acc = 0.0;
    for(int d=0;d<128;d++) acc += (double)Wval[j*128+d] * (double)Wg[d*8+e];
    Wvg[t] = acc;
  }
  for(int q=t;q<512;q+=256){
    int p = q>>3, e = q&7;
    double acc = 0.0;
    for(int d=0;d<128;d++) acc += (double)pef[p*128+d] * (double)Wg[d*8+e];
    peg[q] = acc;
  }
}

__global__ void k_wt(const float* __restrict__ in, u16* __restrict__ outp, int R, int C){
  __shared__ float tile[32][33];
  int e = blockIdx.z;
  int c0 = blockIdx.x*32, r0 = blockIdx.y*32;
  const float* src = in + (size_t)e*R*C;
  u16* dst = outp + (size_t)e*R*C;
  int tx=threadIdx.x, ty=threadIdx.y;
  for(int i=ty;i<32;i+=8){
    int r=r0+i, c=c0+tx;
    tile[i][tx] = (r<R && c<C) ? src[(size_t)r*C+c] : 0.f;
  }
  __syncthreads();
  for(int i=ty;i<32;i+=8){
    int c=c0+i, r=r0+tx;
    if(c<C && r<R) dst[(size_t)c*R + r] = f2bf(tile[tx][i]);
  }
}

// permuted head-weight transpose: WhT2[o][p*128+d] = W_head[(d*64+p)*96 + o]
__global__ void k_wh(const float* __restrict__ Wh, u16* __restrict__ WhT2){
  __shared__ float tile[32][33];
  int d0 = blockIdx.x*32, o0 = blockIdx.y*32, p = blockIdx.z;
  int tx = threadIdx.x, ty = threadIdx.y;
  for(int i=ty;i<32;i+=8){
    int r = (d0+i)*64 + p;
    tile[i][tx] = Wh[(size_t)r*96 + o0 + tx];
  }
  __syncthreads();
  for(int i=ty;i<32;i+=8){
    int o = o0+i;
    WhT2[(size_t)o*DP_ + p*128 + d0 + tx] = f2bf(tile[tx][i]);
  }
}

// fused patch-embed (fp32) + gating (fp64 logits) per (b,v) row
__global__ __launch_bounds__(256) void k_embgate(
    const float* __restrict__ xT, const float* __restrict__ meanp, const float* __restrict__ rstdp,
    const double* __restrict__ meand, const double* __restrict__ rstdd,
    const float* __restrict__ Wval, const float* __restrict__ pe,
    const double* __restrict__ Wvg, const double* __restrict__ peg,
    u16* __restrict__ tglob, int* __restrict__ topip, float2* __restrict__ gatep,
    float* __restrict__ pg, int* __restrict__ pib)
{
  __shared__ __align__(16) float xn[520];
  __shared__ double xnd[520];
  __shared__ double lgt[64][9];
  int r = blockIdx.x, t = threadIdx.x;
  float mean = meanp[r], rstd = rstdp[r];
  double md = meand[r], rsd = rstdd[r];
  float x0f = xT[(size_t)r*L_ + t], x1f = xT[(size_t)r*L_ + 256 + t];
  float v0 = (x0f - mean)*rstd;
  float v1 = (x1f - mean)*rstd;
  double d0v = ((double)x0f - md)*rsd;
  double d1v = ((double)x1f - md)*rsd;
  xn[t] = v0; xn[t+256] = v1;
  xnd[t] = d0v; xnd[t+256] = d1v;
  if(t==255){
    #pragma unroll
    for(int i=512;i<520;i++){ xn[i]=v1; xnd[i]=d1v; }
  }
  int d0 = (t & 63)*2;
  int p0 = t >> 6;
  float2 w[16];
  #pragma unroll
  for(int j=0;j<16;j++) w[j] = *(const float2*)(Wval + j*128 + d0);
  __syncthreads();

  // ---- embed ----
  for(int p=p0;p<64;p+=4){
    const float4* xp = (const float4*)(xn + p*8);
    float4 a0_=xp[0], a1_=xp[1], a2_=xp[2], a3_=xp[3];
    float xv[16];
    *(float4*)(xv+0)=a0_; *(float4*)(xv+4)=a1_; *(float4*)(xv+8)=a2_; *(float4*)(xv+12)=a3_;
    float2 pw = *(const float2*)(pe + p*128 + d0);
    float a0 = pw.x, a1 = pw.y;
    #pragma unroll
    for(int j=0;j<16;j++){ a0 += xv[j]*w[j].x; a1 += xv[j]*w[j].y; }
    u32 packed = (u32)f2bf(a0) | ((u32)f2bf(a1)<<16);
    *(u32*)(tglob + ((size_t)(r*64+p)*128 + d0)) = packed;
  }

  // ---- gate logits (fp64) ----
  for(int q=t;q<512;q+=256){
    int p = q>>3, e = q&7;
    double acc = peg[q];
    #pragma unroll
    for(int j=0;j<16;j++) acc += xnd[p*8+j]*Wvg[j*8+e];
    lgt[p][e] = acc;
  }
  __syncthreads();
  if(t<64){
    int token = r*64 + t;
    double l0[8];
    #pragma unroll
    for(int e=0;e<8;e++) l0[e]=lgt[t][e];
    double mx=l0[0];
    #pragma unroll
    for(int e=1;e<8;e++) mx = fmax(mx,l0[e]);
    int i1=0; double b1v=l0[0];
    #pragma unroll
    for(int e=1;e<8;e++) if(l0[e]>b1v){b1v=l0[e]; i1=e;}
    int i2=-1; double b2v=-1e300;
    #pragma unroll
    for(int e=0;e<8;e++) if(e!=i1 && l0[e]>b2v){b2v=l0[e]; i2=e;}
    float pr[8]; float sum=0.f;
    #pragma unroll
    for(int e=0;e<8;e++){ pr[e]=__expf((float)(l0[e]-mx)); sum+=pr[e]; }
    float inv = 1.f/sum;
    #pragma unroll
    for(int e=0;e<8;e++) pr[e]*=inv;
    topip[token] = i1 | (i2<<8);
    gatep[token] = make_float2(pr[i1], pr[i2]);
    float lse = (float)mx + __logf(sum);
    #pragma unroll
    for(int e=0;e<8;e++){
      float v = pr[e];
      for(int o=32;o>0;o>>=1) v += __shfl_down(v,o);
      if(t==0) pg[r*12+e] = v;
    }
    {
      float z = lse*lse;
      for(int o=32;o>0;o>>=1) z += __shfl_down(z,o);
      if(t==0) pg[r*12+8] = z;
    }
    #pragma unroll
    for(int e=0;e<8;e++){
      u64 m1 = __ballot(i1==e);
      u64 m2 = __ballot(i2==e);
      if(t==0){
        pib[r*16+e]   = (int)__popcll(m1);
        pib[r*16+8+e] = (int)__popcll(m2);
      }
    }
  }
}

__global__ __launch_bounds__(256) void k_aux(const float* __restrict__ pg, const int* __restrict__ pib,
                                             int* __restrict__ ci, float* __restrict__ dout){
  __shared__ double sd[256];
  __shared__ int si[256];
  __shared__ double totd[9];
  __shared__ int toti[16];
  int t = threadIdx.x;
  double accd[9]; int acci[16];
  #pragma unroll
  for(int c=0;c<9;c++) accd[c]=0.0;
  #pragma unroll
  for(int c=0;c<16;c++) acci[c]=0;
  for(int r=t;r<NRW;r+=256){
    #pragma unroll
    for(int c=0;c<9;c++) accd[c] += (double)pg[r*12+c];
    #pragma unroll
    for(int c=0;c<16;c++) acci[c] += pib[r*16+c];
  }
  for(int c=0;c<9;c++){
    sd[t]=accd[c]; __syncthreads();
    for(int o=128;o>0;o>>=1){ if(t<o) sd[t]+=sd[t+o]; __syncthreads(); }
    if(t==0) totd[c]=sd[0];
    __syncthreads();
  }
  for(int c=0;c<16;c++){
    si[t]=acci[c]; __syncthreads();
    for(int o=128;o>0;o>>=1){ if(t<o) si[t]+=si[t+o]; __syncthreads(); }
    if(t==0) toti[c]=si[0];
    __syncthreads();
  }
  if(t==0){
    const double invN = 1.0/(double)NTOK;
    double bal = 0.0;
    int es1=0, bs1=0, es2=0, bs2=0;
    for(int e=0;e<8;e++){
      int c1 = toti[e], c2 = toti[8+e];
      bal += (totd[e]*invN) * ((double)(c1+c2) * invN * 0.5);
      ci[32+e]=es1; ci[16+e]=es1; ci[50+e]=bs1;
      ci[41+e]=es2; ci[24+e]=es2; ci[59+e]=bs2;
      es1 += c1; bs1 += (c1+127)>>7;
      es2 += c2; bs2 += (c2+127)>>7;
    }
    ci[40]=es1; ci[58]=bs1;
    ci[49]=es2; ci[67]=bs2;
    dout[493056] = (float)(0.01*8.0*bal + 0.001*(totd[8]*invN));
  }
}

__global__ __launch_bounds__(256) void k_scatter(const int* __restrict__ topip,
    const float2* __restrict__ gatep, int* __restrict__ ci,
    int* __restrict__ btok, float* __restrict__ bgt){
  __shared__ int lc[16]; __shared__ int lb[16];
  int t = threadIdx.x;
  int token = blockIdx.x*256 + t;
  if(t<16) lc[t]=0;
  __syncthreads();
  int ti = topip[token];
  float2 g = gatep[token];
  int e1 = ti & 255, e2 = (ti>>8)&255;
  int r1 = atomicAdd(&lc[e1],1);
  int r2 = atomicAdd(&lc[8+e2],1);
  __syncthreads();
  if(t<8)            lb[t] = atomicAdd(&ci[16+t],   lc[t]);
  else if(t<16)      lb[t] = atomicAdd(&ci[24+t-8], lc[t]);
  __syncthreads();
  int p1 = lb[e1]+r1, p2 = lb[8+e2]+r2;
  btok[p1] = token;         bgt[p1] = g.x;
  btok[NBUCK+p2] = token;   bgt[NBUCK+p2] = g.y;
}

// fused per-expert FFN v7: A in regs, swapped GEMM2 (D col=token) -> direct
// global-store epilogue (no LDS transpose), packed-f32 gelu, dbuf W staging.
__global__ __launch_bounds__(256,3) void k_expert(
    const u16* __restrict__ tglob,
    const u16* __restrict__ W1T, const u16* __restrict__ W2T,
    const float* __restrict__ b1g, const float* __restrict__ b2g,
    const int* __restrict__ ci,
    const int* __restrict__ btok, const float* __restrict__ bgt,
    u16* __restrict__ outg, int slot)
{
  // Wb[i]: W1c [32][136] at 0 (4352 u16), W2c [128][40] at 4352 (5120 u16)
  __shared__ __align__(16) u16 Wb[2][9472];   // 37888 B
  __shared__ __align__(16) u16 Ss[128*40];    // 10240 B (wave-private slices)
  __shared__ float b2s[128];                  // 512 B

  int bid = blockIdx.x, t = threadIdx.x;
  int stB = 32 + slot*9, bsB = 50 + slot*9;
  int boff = slot*NBUCK;
  if(bid >= ci[bsB+8]) return;
  int e = 0;
  #pragma unroll
  for(int k2=1;k2<8;k2++) if(bid >= ci[bsB+k2]) e = k2;
  int row0 = ci[stB+e] + (bid - ci[bsB+e])*128;
  int rend = ci[stB+e+1];

  if(t<128) b2s[t] = b2g[e*128+t];

  int wid = t>>6, lane = t&63;
  int m = lane&31, hi = lane>>5;
  int rb = wid*32;                 // wave owns token rows rb..rb+31

  // ---- A gather directly to registers (MFMA A-frag layout) ----
  int posA = row0 + rb + m;
  bool valid = posA < rend;
  int tokA = valid ? btok[boff+posA] : 0;
  float gt  = valid ? bgt[boff+posA] : 0.f;
  const u16* arow = tglob + (size_t)tokA*128 + hi*8;
  bf16x8 areg[8];
  #pragma unroll
  for(int ks=0;ks<8;ks++) areg[ks] = *(const bf16x8*)(arow + ks*16);

  // staging thread roles
  int hr = t>>3, q = t&7;          // W1c: row hr (32), 16 u16 at q*16
  int dr = t>>1, q2 = t&1;         // W2c: row dr (128), 16 u16 at q2*16

  { // stage buffer 0 (hc=0)
    const u16* s1 = W1T + ((size_t)e*H_ + hr)*128 + q*16;
    u16* d1 = &Wb[0][hr*136 + q*16];
    *(uint4*)(d1)   = *(const uint4*)(s1);
    *(uint4*)(d1+8) = *(const uint4*)(s1+8);
    const u16* s2 = W2T + ((size_t)e*D_ + dr)*H_ + q2*16;
    u16* d2 = &Wb[0][4352 + dr*40 + q2*16];
    *(uint4*)(d2)   = *(const uint4*)(s2);
    *(uint4*)(d2+8) = *(const uint4*)(s2+8);
  }
  __syncthreads();

  f32x16 accO[4];
  const f32x16 z16 = {0,0,0,0,0,0,0,0,0,0,0,0,0,0,0,0};
  #pragma unroll
  for(int nt=0;nt<4;nt++) accO[nt] = z16;

  for(int hc=0;hc<16;hc++){
    const u16* W1c = &Wb[hc&1][0];
    const u16* W2c = &Wb[hc&1][4352];
    uint4 l0,l1,l2,l3;
    if(hc<15){
      const u16* s1 = W1T + ((size_t)e*H_ + (hc+1)*32 + hr)*128 + q*16;
      l0 = *(const uint4*)(s1); l1 = *(const uint4*)(s1+8);
      const u16* s2 = W2T + ((size_t)e*D_ + dr)*H_ + (hc+1)*32 + q2*16;
      l2 = *(const uint4*)(s2); l3 = *(const uint4*)(s2+8);
    }
    // GEMM1: S(128x32) = A(regs)@W1c  (D: col=h, row=token)
    f32x16 acc1 = z16;
    #pragma unroll
    for(int ks=0;ks<8;ks++){
      bf16x8 b = *(const bf16x8*)(W1c + m*136 + ks*16 + hi*8);
      acc1 = MFMA32(areg[ks], b, acc1);
    }
    float bv = b1g[e*H_ + hc*32 + m];
    #pragma unroll
    for(int pr=0; pr<8; pr++){
      int reg = pr*2;
      int rl = (reg&3) + 8*(reg>>2) + 4*hi;
      f32x2 v; v.x = acc1[reg]+bv; v.y = acc1[reg+1]+bv;
      f32x2 g2 = gelu2(v);
      u16* sp = Ss + (rb+rl)*40 + m;
      sp[0]  = f2bf(g2.x);
      sp[40] = f2bf(g2.y);
    }
    // GEMM2 (swapped): accO[mt] = W2c-frag(A) x S-frag(B) -> D col=token
    #pragma unroll
    for(int ks=0;ks<2;ks++){
      bf16x8 sfrag = *(const bf16x8*)(Ss + (rb+m)*40 + ks*16 + hi*8);
      #pragma unroll
      for(int mt=0;mt<4;mt++){
        bf16x8 wfrag = *(const bf16x8*)(W2c + (mt*32+m)*40 + ks*16 + hi*8);
        accO[mt] = MFMA32(wfrag, sfrag, accO[mt]);
      }
    }
    if(hc<15){
      u16* d1 = &Wb[(hc+1)&1][hr*136 + q*16];
      *(uint4*)(d1)   = l0; *(uint4*)(d1+8) = l1;
      u16* d2 = &Wb[(hc+1)&1][4352 + dr*40 + q2*16];
      *(uint4*)(d2)   = l2; *(uint4*)(d2+8) = l3;
      __syncthreads();               // one barrier per hc
    }
  }

  // ---- epilogue: lane owns token tokA; d in contiguous 4-runs ----
  u16* dst = outg + (size_t)tokA*128;
  #pragma unroll
  for(int mt=0;mt<4;mt++){
    #pragma unroll
    for(int rg=0;rg<4;rg++){
      int dd = mt*32 + rg*8 + hi*4;
      float4 bb = *(const float4*)(b2s + dd);
      float f0 = (accO[mt][rg*4+0] + bb.x)*gt;
      float f1 = (accO[mt][rg*4+1] + bb.y)*gt;
      float f2 = (accO[mt][rg*4+2] + bb.z)*gt;
      float f3 = (accO[mt][rg*4+3] + bb.w)*gt;
      u32 w0 = (u32)f2bf(f0) | ((u32)f2bf(f1)<<16);
      u32 w1 = (u32)f2bf(f2) | ((u32)f2bf(f3)<<16);
      if(valid){
        u32* dp = (u32*)(dst + dd);
        if(slot==1){
          w0 = bfadd2(w0, dp[0]);
          w1 = bfadd2(w1, dp[1]);
        }
        uint2 wv; wv.x = w0; wv.y = w1;
        *(uint2*)dp = wv;
      }
    }
  }
}

// head GEMM: A = outg (k' = p*128+d natural order), B = WhT2[o][k'].
// wave owns 16 rows, 8-way K-split, no LDS, plain stores to dec8.
__global__ __launch_bounds__(256) void k_head(const u16* __restrict__ Aout,
    const u16* __restrict__ WhT2, float* __restrict__ dec8){
  int bid = blockIdx.x;                 // 81 mtiles x 8 ksegs
  int mb = bid>>3, kseg = bid&7;
  int t = threadIdx.x, wid = t>>6, lane = t&63;
  int quad = lane>>4, li = lane&15;
  int r0 = mb*64 + wid*16;
  int rowA = r0 + li; if(rowA >= NRW) rowA = NRW-1;
  const u16* aptr = Aout + (size_t)rowA*DP_ + kseg*1024 + quad*8;
  const u16* bptr = WhT2 + (size_t)li*DP_  + kseg*1024 + quad*8;
  f32x4 acc[6];
  #pragma unroll
  for(int j=0;j<6;j++) acc[j]=(f32x4){0,0,0,0};
  #pragma unroll 4
  for(int ks=0;ks<32;ks++){
    bf16x8 af = *(const bf16x8*)(aptr + ks*32);
    #pragma unroll
    for(int nt=0;nt<6;nt++){
      bf16x8 bw = *(const bf16x8*)(bptr + (size_t)nt*16*DP_ + ks*32);
      acc[nt] = MFMA16(af, bw, acc[nt]);
    }
  }
  float* dst = dec8 + (size_t)kseg*NRW*96;
  #pragma unroll
  for(int nt=0;nt<6;nt++)
    #pragma unroll
    for(int rg=0;rg<4;rg++){
      int mm = r0 + quad*4 + rg;
      if(mm < NRW) dst[(size_t)mm*96 + nt*16 + li] = acc[nt][rg];
    }
}

// sum 8 k-segments + transpose + bias + denorm
__global__ void k_final(const float* __restrict__ dec8, const float* __restrict__ bhead,
    const float* __restrict__ stdp, const float* __restrict__ meanp, float* __restrict__ outp){
  __shared__ float s[64*97];
  int b = blockIdx.y, v0 = blockIdx.x*64;
  int t = threadIdx.x;
  for(int i=t;i<6144;i+=256){
    int vi = i/96, o = i - vi*96;
    int v = v0+vi;
    float acc = 0.f;
    if(v<NV_){
      size_t base = (size_t)(b*NV_+v)*96 + o;
      #pragma unroll
      for(int ks=0;ks<8;ks++) acc += dec8[(size_t)ks*NRW*96 + base];
    }
    s[vi*97+o] = acc;
  }
  __syncthreads();
  for(int i=t;i<6144;i+=256){
    int o = i>>6, vi = i&63;
    int v = v0+vi;
    if(v<NV_){
      int r = b*NV_+v;
      outp[((size_t)b*96 + o)*NV_ + v] = (s[vi*97+o] + bhead[o])*stdp[r] + meanp[r];
    }
  }
}

// ============ launcher ============
extern "C" void kernel_launch(void* const* d_in, const int* in_sizes, int n_in,
                              void* d_out, int out_size, void* d_ws, size_t ws_size,
                              hipStream_t stream){
  const float* x_enc = (const float*)d_in[0];
  const float* W_val = (const float*)d_in[4];
  const float* W_g   = (const float*)d_in[5];
  const float* W1    = (const float*)d_in[6];
  const float* b1    = (const float*)d_in[7];
  const float* W2    = (const float*)d_in[8];
  const float* b2    = (const float*)d_in[9];
  const float* W_head= (const float*)d_in[10];
  const float* b_head= (const float*)d_in[11];
  float* outp = (float*)d_out;
  char* ws = (char*)d_ws;

  float* meanp = (float*)(ws+OFF_MEAN);
  float* rstdp = (float*)(ws+OFF_RSTD);
  float* stdp  = (float*)(ws+OFF_STD);
  float* xT    = (float*)(ws+OFF_XT);
  float* pe    = (float*)(ws+OFF_PE);
  u16*   W1T   = (u16*)(ws+OFF_W1T);
  u16*   W2T   = (u16*)(ws+OFF_W2T);
  u16*   WhT2  = (u16*)(ws+OFF_WHT);
  u16*   tglob = (u16*)(ws+OFF_T);
  float* dec8  = (float*)(ws+OFF_T);    // aliases tglob (dead after expert gather)
  int*   topip = (int*)(ws+OFF_TOPI);
  float2* gatep= (float2*)(ws+OFF_GATE);
  int*   ci    = (int*)(ws+OFF_CNTR+128);
  int*   btok  = (int*)(ws+OFF_BTOK);
  float* bgt   = (float*)(ws+OFF_BGT);
  u16*   outg  = (u16*)(ws+OFF_OUT);
  double* meand= (double*)(ws+OFF_MEAND);
  double* rstdd= (double*)(ws+OFF_RSTDD);
  double* Wvg  = (double*)(ws+OFF_WVG);
  double* peg  = (double*)(ws+OFF_PEG);
  float* pg    = (float*)(ws+OFF_PG);
  int*   pib   = (int*)(ws+OFF_PI);

  hipMemsetAsync(ws+OFF_CNTR, 0, 1024, stream);

  k_xt<<<dim3(11,16,B_), dim3(32,8), 0, stream>>>(x_enc, xT);
  k_stats<<<NRW, 256, 0, stream>>>(xT, meanp, rstdp, stdp, meand, rstdd);
  k_prep<<<1, 256, 0, stream>>>(W_val, W_g, pe, Wvg, peg);
  k_wt<<<dim3(16,4,E_), dim3(32,8), 0, stream>>>(W1, W1T, 128, 512);
  k_wt<<<dim3(4,16,E_), dim3(32,8), 0, stream>>>(W2, W2T, 512, 128);
  k_wh<<<dim3(4,3,64), dim3(32,8), 0, stream>>>(W_head, WhT2);
  k_embgate<<<NRW, 256, 0, stream>>>(xT, meanp, rstdp, meand, rstdd, W_val, pe,
                                     Wvg, peg, tglob, topip, gatep, pg, pib);
  k_aux<<<1, 256, 0, stream>>>(pg, pib, ci, outp);
  k_scatter<<<NTOK/256, 256, 0, stream>>>(topip, gatep, ci, btok, bgt);
  k_expert<<<2576, 256, 0, stream>>>(tglob, W1T, W2T, b1, b2, ci, btok, bgt, outg, 0);
  k_expert<<<2576, 256, 0, stream>>>(tglob, W1T, W2T, b1, b2, ci, btok, bgt, outg, 1);
  k_head<<<648, 256, 0, stream>>>(outg, WhT2, dec8);
  k_final<<<dim3(6,B_), 256, 0, stream>>>(dec8, b_head, stdp, meanp, outp);
}